// Round 5
// baseline (2409.594 us; speedup 1.0000x reference)
//
#include <hip/hip_runtime.h>
#include <math.h>

// TGCN: B=16, T=12, N=1000, H=128, NL=2
#define BB 16
#define TT 12
#define NN 1000
#define HH 128
#define CC 129
#define NROW 16000
#define GR 160            // Gfull rows per b (0:x, 1..128:h^T, 129..159:zero)
#define KP 1024           // k / col dim of Gfull rows
#define CP2 160           // stage-2 K (c padded)
#define PRS 148           // Pred stride (f32)
#define SPS 168           // sP stride (bf16)

typedef __attribute__((ext_vector_type(4))) float f32x4;
typedef __attribute__((ext_vector_type(8))) __bf16 bf16x8;

__device__ __forceinline__ float sigmoidf_(float x) { return 1.0f / (1.0f + expf(-x)); }

// ---------------- laplacian ----------------
__global__ void k_softmax(const float* __restrict__ adj, float* __restrict__ a) {
    int i = blockIdx.x;
    int t = threadIdx.x;
    __shared__ float red[256];
    float m = -1e30f;
    for (int j = t; j < NN; j += 256) m = fmaxf(m, adj[i * NN + j]);
    red[t] = m; __syncthreads();
    for (int s = 128; s > 0; s >>= 1) { if (t < s) red[t] = fmaxf(red[t], red[t + s]); __syncthreads(); }
    m = red[0]; __syncthreads();
    float sum = 0.f;
    for (int j = t; j < NN; j += 256) sum += expf(adj[i * NN + j] - m);
    red[t] = sum; __syncthreads();
    for (int s = 128; s > 0; s >>= 1) { if (t < s) red[t] += red[t + s]; __syncthreads(); }
    float inv = 1.0f / red[0];
    for (int j = t; j < NN; j += 256) a[i * NN + j] = expf(adj[i * NN + j] - m) * inv;
}

__global__ __launch_bounds__(256) void k_build_Lt(const float* __restrict__ a, __bf16* __restrict__ Lb) {
    __shared__ float s[64][65];
    int bi = blockIdx.x * 64;
    int bj = blockIdx.y * 64;
    int t = threadIdx.x;
    for (int q = t; q < 64 * 64; q += 256) {
        int r = q >> 6, c = q & 63;
        int jj = bj + r, ii = bi + c;
        s[r][c] = (jj < NN && ii < NN) ? a[jj * NN + ii] : 0.f;
    }
    __syncthreads();
    for (int q = t; q < 64 * 64; q += 256) {
        int r = q >> 6, c = q & 63;
        int ii = bi + r, jj = bj + c;
        if (ii < NN && jj < NN)
            Lb[(size_t)ii * KP + jj] = (__bf16)(0.5f * (s[c][r] + (ii == jj ? 1.0f : 0.0f)));
    }
}

// ---------------- one-time weight prep ----------------
__global__ void k_prep(const float* __restrict__ wih, const float* __restrict__ whh,
                       const float* __restrict__ proj_w, const float* __restrict__ ow1,
                       const float* __restrict__ ow2, const float* __restrict__ gc1_w,
                       const float* __restrict__ gc2_w,
                       __bf16* __restrict__ WihB, __bf16* __restrict__ WhhB,
                       __bf16* __restrict__ projB, __bf16* __restrict__ w1B,
                       __bf16* __restrict__ w2B, __bf16* __restrict__ W1t,
                       __bf16* __restrict__ W2t) {
    int idx = blockIdx.x * 256 + threadIdx.x;
    if (idx < 49152) { WihB[idx] = (__bf16)wih[idx]; return; }
    idx -= 49152;
    if (idx < 49152) { WhhB[idx] = (__bf16)whh[idx]; return; }
    idx -= 49152;
    if (idx < 16384) { projB[idx] = (__bf16)proj_w[idx]; return; }
    idx -= 16384;
    if (idx < 32768) { w1B[idx] = (__bf16)ow1[idx]; return; }
    idx -= 32768;
    if (idx < 32768) { w2B[idx] = (__bf16)ow2[idx]; return; }
    idx -= 32768;
    if (idx < 2 * 256 * CP2) {
        int l = idx / (256 * CP2); int r = idx % (256 * CP2); int o = r / CP2, c = r % CP2;
        W1t[idx] = (c < CC) ? (__bf16)gc1_w[((size_t)l * CC + c) * 256 + o] : (__bf16)0.f;
        return;
    }
    idx -= 2 * 256 * CP2;
    if (idx < 2 * 128 * CP2) {
        int l = idx / (128 * CP2); int r = idx % (128 * CP2); int o = r / CP2, c = r % CP2;
        W2t[idx] = (c < CC) ? (__bf16)gc2_w[((size_t)l * CC + c) * 128 + o] : (__bf16)0.f;
    }
}

// Gfull0 row0 = x at t=0
__global__ void k_prep_x(const float* __restrict__ inp, __bf16* __restrict__ G0) {
    int idx = blockIdx.x * 256 + threadIdx.x;
    if (idx >= BB * 1024) return;
    int b = idx >> 10, k = idx & 1023;
    G0[(size_t)b * GR * KP + k] = (k < NN) ? (__bf16)inp[(size_t)b * TT * NN + k] : (__bf16)0.f;
}

// ---------------- fused graph-conv + weight matmul + epilogue (LDS-free stage-1) ----------------
// 256 threads = 4 waves: wk = k-half, wc = c-split (c 0..79 / 80..143).
// Stage 1 (global->reg MFMA): P[m=64][c=144] = sum_k L[m0+m,k] * Gfull[b][c,k]
// Stage 2: S[m][o] = sum_c P[m,c] * Wt[o,c]   (K=160, o split across 4 waves)
template<int MODE>
__global__ __launch_bounds__(256) void k_fused(
    const __bf16* __restrict__ Lb, const __bf16* __restrict__ Gfull,
    const __bf16* __restrict__ Wt, const float* __restrict__ bias,
    __bf16* __restrict__ GB, float* __restrict__ u, float* __restrict__ h,
    const float* __restrict__ x_in, int xstride,
    const float* __restrict__ res_w, const float* __restrict__ res_b,
    const float* __restrict__ ln_g, const float* __restrict__ ln_b,
    float* __restrict__ x_out, __bf16* __restrict__ Gnext,
    __bf16* __restrict__ GhSelf, __bf16* __restrict__ outT, int store_out) {
    __shared__ __align__(16) char smem[59392];
    __shared__ float sScal[640];
    float* Pred = (float*)smem;                   // [64][148] f32
    __bf16* sP = (__bf16*)(smem + 37888);         // [64][168] bf16
    __bf16* sGT = (__bf16*)smem;                  // MODE0 overlay [256][72]
    __bf16* sT = (__bf16*)smem;                   // MODE1 overlay [128][72]
    __bf16* sO = (__bf16*)(smem + 18432);         // MODE1 overlay [64][136]
    float* sSt = (float*)(smem + 35840);          // MODE1 overlay [2][256]

    int tid = threadIdx.x;
    int wg = blockIdx.x;
    int b = wg & 15;                 // b%8 == XCD id -> G[b] stays in home L2
    int m0 = (wg >> 4) * 64;
    int wave = tid >> 6, lane = tid & 63;
    int lr = lane & 15, lk = lane >> 4;
    int wk = wave >> 1;              // k-half
    int wc = wave & 1;               // c-split: 5 frags (c0=0) or 4 frags (c0=80)

    if (MODE == 0) {
        if (tid < 256) sScal[tid] = bias[tid];
    } else {
        if (tid < 128) {
            sScal[tid] = bias[tid];
            sScal[128 + tid] = res_w[tid];
            sScal[256 + tid] = res_b[tid];
            sScal[384 + tid] = ln_g[tid];
            sScal[512 + tid] = ln_b[tid];
        }
    }

    int c0 = wc * 80;
    const __bf16* lptr = Lb + ((size_t)(m0 + lr)) * KP + wk * 512 + lk * 8;
    const __bf16* gptr = Gfull + ((size_t)b * GR + c0 + lr) * KP + wk * 512 + lk * 8;

    f32x4 acc[4][5];
#pragma unroll
    for (int i = 0; i < 4; i++)
#pragma unroll
        for (int j = 0; j < 5; j++) acc[i][j] = (f32x4){0.f, 0.f, 0.f, 0.f};

#define LD1(A_, B_, KOFF)                                                              \
    {                                                                                  \
        _Pragma("unroll")                                                              \
        for (int mf = 0; mf < 4; mf++) A_[mf] = *(const bf16x8*)(lptr + mf * 16384 + (KOFF)); \
        _Pragma("unroll")                                                              \
        for (int cf = 0; cf < 5; cf++)                                                 \
            if (wc == 0 || cf < 4) B_[cf] = *(const bf16x8*)(gptr + cf * 16384 + (KOFF)); \
    }
#define MM1(A_, B_)                                                                    \
    {                                                                                  \
        _Pragma("unroll")                                                              \
        for (int mf = 0; mf < 4; mf++)                                                 \
            _Pragma("unroll")                                                          \
            for (int cf = 0; cf < 5; cf++)                                             \
                if (wc == 0 || cf < 4)                                                 \
                    acc[mf][cf] = __builtin_amdgcn_mfma_f32_16x16x32_bf16(A_[mf], B_[cf], acc[mf][cf], 0, 0, 0); \
    }

    {
        bf16x8 aX[4], bX[5], aY[4], bY[5];
        LD1(aX, bX, 0);
        for (int kk = 0; kk < 512; kk += 64) {
            LD1(aY, bY, kk + 32);
            MM1(aX, bX);
            if (kk + 64 < 512) LD1(aX, bX, kk + 64);
            MM1(aY, bY);
        }
    }
#undef LD1
#undef MM1

    // k-half reduction -> bf16 P in sP
    if (wk == 1) {
#pragma unroll
        for (int mf = 0; mf < 4; mf++)
#pragma unroll
            for (int cf = 0; cf < 5; cf++) {
                if (wc == 1 && cf == 4) continue;
#pragma unroll
                for (int i = 0; i < 4; i++)
                    Pred[(mf * 16 + lk * 4 + i) * PRS + c0 + cf * 16 + lr] = acc[mf][cf][i];
            }
    }
    __syncthreads();
    if (wk == 0) {
#pragma unroll
        for (int mf = 0; mf < 4; mf++)
#pragma unroll
            for (int cf = 0; cf < 5; cf++) {
                if (wc == 1 && cf == 4) continue;
#pragma unroll
                for (int i = 0; i < 4; i++) {
                    float v = acc[mf][cf][i] + Pred[(mf * 16 + lk * 4 + i) * PRS + c0 + cf * 16 + lr];
                    sP[(mf * 16 + lk * 4 + i) * SPS + c0 + cf * 16 + lr] = (__bf16)v;
                }
            }
    }
    for (int q = tid; q < 64 * 16; q += 256) sP[(q >> 4) * SPS + 144 + (q & 15)] = (__bf16)0.f;
    __syncthreads();

    // Stage 2: o split across 4 waves
    constexpr int NOF = (MODE == 0) ? 4 : 2;
    int o0 = wave * NOF * 16;
    f32x4 accs[4][NOF];
#pragma unroll
    for (int i = 0; i < 4; i++)
#pragma unroll
        for (int j = 0; j < NOF; j++) accs[i][j] = (f32x4){0.f, 0.f, 0.f, 0.f};
#pragma unroll
    for (int kk2 = 0; kk2 < CP2; kk2 += 32) {
        bf16x8 pa[4];
#pragma unroll
        for (int mf2 = 0; mf2 < 4; mf2++)
            pa[mf2] = *(const bf16x8*)&sP[(mf2 * 16 + lr) * SPS + kk2 + lk * 8];
#pragma unroll
        for (int of = 0; of < NOF; of++) {
            bf16x8 wb = *(const bf16x8*)&Wt[(size_t)(o0 + of * 16 + lr) * CP2 + kk2 + lk * 8];
#pragma unroll
            for (int mf2 = 0; mf2 < 4; mf2++)
                accs[mf2][of] = __builtin_amdgcn_mfma_f32_16x16x32_bf16(pa[mf2], wb, accs[mf2][of], 0, 0, 0);
        }
    }

    if (MODE == 0) {
        // copy x row0 slice into GB (cell's concat needs it)
        if (tid < 8)
            *(bf16x8*)&GB[(size_t)b * GR * KP + m0 + tid * 8] =
                *(const bf16x8*)&Gfull[(size_t)b * GR * KP + m0 + tid * 8];
        bool clean = (m0 + 64 <= 500);
        if (clean) {
#pragma unroll
            for (int mf2 = 0; mf2 < 4; mf2++)
#pragma unroll
                for (int of = 0; of < NOF; of++) {
                    int o = o0 + of * 16 + lr;
                    float bv = sScal[o];
#pragma unroll
                    for (int i = 0; i < 4; i++)
                        sGT[o * 72 + mf2 * 16 + lk * 4 + i] = (__bf16)sigmoidf_(accs[mf2][of][i] + bv);
                }
            __syncthreads();
            for (int q = tid; q < 128 * 16; q += 256) {
                int j = q >> 4;
                int rnc = (q & 15) * 4;
                size_t gidx = ((size_t)b * GR + 1 + j) * KP + 2 * m0 + rnc * 2;
                bf16x8 hv = *(const bf16x8*)&Gfull[gidx];
                bf16x8 rv;
#pragma unroll
                for (int e = 0; e < 8; e++) {
                    int rnl = rnc + (e >> 1);
                    int hi = e & 1;
                    float g = (float)sGT[(hi * 128 + j) * 72 + rnl];
                    rv[e] = (__bf16)(g * (float)hv[e]);
                }
                *(bf16x8*)&GB[gidx] = rv;
            }
        } else {
#pragma unroll
            for (int mf2 = 0; mf2 < 4; mf2++)
#pragma unroll
                for (int of = 0; of < NOF; of++) {
                    int o = o0 + of * 16 + lr;
                    int j = o & 127, hi = o >> 7;
                    float bv = sScal[o];
#pragma unroll
                    for (int i = 0; i < 4; i++) {
                        int m = m0 + mf2 * 16 + lk * 4 + i;
                        if (m >= NN) continue;
                        float g = sigmoidf_(accs[mf2][of][i] + bv);
                        if (m < 500) {
                            size_t gi = ((size_t)b * GR + 1 + j) * KP + 2 * m + hi;
                            GB[gi] = (__bf16)(g * (float)Gfull[gi]);
                        } else {
                            u[((size_t)b * NN + 2 * (m - 500) + hi) * HH + j] = g;
                        }
                    }
                }
        }
    } else {
        float hnv[4][NOF][4];
        float s_[4][4], ss_[4][4];
#pragma unroll
        for (int a = 0; a < 4; a++)
#pragma unroll
            for (int i = 0; i < 4; i++) { s_[a][i] = 0.f; ss_[a][i] = 0.f; }
#pragma unroll
        for (int mf2 = 0; mf2 < 4; mf2++)
#pragma unroll
            for (int of = 0; of < NOF; of++) {
                int j = o0 + of * 16 + lr;
                float b2v = sScal[j], rwv = sScal[128 + j], rbv = sScal[256 + j];
#pragma unroll
                for (int i = 0; i < 4; i++) {
                    int m = m0 + mf2 * 16 + lk * 4 + i;
                    int msafe = (m < NN) ? m : (NN - 1);
                    size_t ri = ((size_t)b * NN + msafe) * HH + j;
                    float cv = tanhf(accs[mf2][of][i] + b2v);
                    float uu = u[ri];
                    float hv = h[ri];
                    float hn = uu * hv + (1.f - uu) * cv;
                    if (m < NN) h[ri] = hn;
                    hnv[mf2][of][i] = hn;
                    float xv = (m < NN) ? x_in[(size_t)b * xstride + m] : 0.f;
                    float y = hn + xv * rwv + rbv;
                    accs[mf2][of][i] = y;
                    s_[mf2][i] += y; ss_[mf2][i] += y * y;
                }
            }
#pragma unroll
        for (int msk = 1; msk < 16; msk <<= 1)
#pragma unroll
            for (int a = 0; a < 4; a++)
#pragma unroll
                for (int i = 0; i < 4; i++) {
                    s_[a][i] += __shfl_xor(s_[a][i], msk);
                    ss_[a][i] += __shfl_xor(ss_[a][i], msk);
                }
        if (lr == 0) {
#pragma unroll
            for (int a = 0; a < 4; a++)
#pragma unroll
                for (int i = 0; i < 4; i++) {
                    int ml = a * 16 + lk * 4 + i;
                    sSt[wave * 64 + ml] = s_[a][i];
                    sSt[256 + wave * 64 + ml] = ss_[a][i];
                }
        }
        __syncthreads();
        float mu_[4][4], rs_[4][4];
#pragma unroll
        for (int a = 0; a < 4; a++)
#pragma unroll
            for (int i = 0; i < 4; i++) {
                int ml = a * 16 + lk * 4 + i;
                float S = sSt[ml] + sSt[64 + ml] + sSt[128 + ml] + sSt[192 + ml];
                float SS = sSt[256 + ml] + sSt[320 + ml] + sSt[384 + ml] + sSt[448 + ml];
                float mu = S * (1.f / 128.f);
                float var = SS * (1.f / 128.f) - mu * mu;
                mu_[a][i] = mu;
                rs_[a][i] = rsqrtf(var + 1e-5f);
            }
        float xs_[4][4];
#pragma unroll
        for (int a = 0; a < 4; a++)
#pragma unroll
            for (int i = 0; i < 4; i++) xs_[a][i] = 0.f;
#pragma unroll
        for (int mf2 = 0; mf2 < 4; mf2++)
#pragma unroll
            for (int of = 0; of < NOF; of++) {
                int j = o0 + of * 16 + lr;
                float lg = sScal[384 + j], lb2 = sScal[512 + j];
#pragma unroll
                for (int i = 0; i < 4; i++) {
                    float ov = (accs[mf2][of][i] - mu_[mf2][i]) * rs_[mf2][i] * lg + lb2;
                    accs[mf2][of][i] = ov;
                    xs_[mf2][i] += ov;
                }
            }
#pragma unroll
        for (int msk = 1; msk < 16; msk <<= 1)
#pragma unroll
            for (int a = 0; a < 4; a++)
#pragma unroll
                for (int i = 0; i < 4; i++) xs_[a][i] += __shfl_xor(xs_[a][i], msk);
        __syncthreads();
        if (lr == 0) {
#pragma unroll
            for (int a = 0; a < 4; a++)
#pragma unroll
                for (int i = 0; i < 4; i++)
                    sSt[wave * 64 + a * 16 + lk * 4 + i] = xs_[a][i];
        }
        __syncthreads();
        if (wave == 0 && lr == 0) {
#pragma unroll
            for (int a = 0; a < 4; a++)
#pragma unroll
                for (int i = 0; i < 4; i++) {
                    int ml = a * 16 + lk * 4 + i;
                    int m = m0 + ml;
                    if (m < NN) {
                        float xv = (sSt[ml] + sSt[64 + ml] + sSt[128 + ml] + sSt[192 + ml]) * (1.f / 128.f);
                        if (x_out) x_out[(size_t)b * NN + m] = xv;
                        if (Gnext) Gnext[(size_t)b * GR * KP + m] = (__bf16)xv;
                    }
                }
        }
        // hn -> GhSelf (transposed), out -> outT
#pragma unroll
        for (int mf2 = 0; mf2 < 4; mf2++)
#pragma unroll
            for (int of = 0; of < NOF; of++) {
                int j = o0 + of * 16 + lr;
#pragma unroll
                for (int i = 0; i < 4; i++)
                    sT[j * 72 + mf2 * 16 + lk * 4 + i] = (__bf16)hnv[mf2][of][i];
            }
        if (store_out) {
#pragma unroll
            for (int mf2 = 0; mf2 < 4; mf2++)
#pragma unroll
                for (int of = 0; of < NOF; of++) {
                    int j = o0 + of * 16 + lr;
#pragma unroll
                    for (int i = 0; i < 4; i++)
                        sO[(mf2 * 16 + lk * 4 + i) * 136 + j] = (__bf16)accs[mf2][of][i];
                }
        }
        __syncthreads();
        for (int q = tid; q < 128 * 8; q += 256) {
            int j = q >> 3, mc = (q & 7) * 8;
            if (m0 + mc < NN)
                *(bf16x8*)&GhSelf[((size_t)b * GR + 1 + j) * KP + m0 + mc] = *(const bf16x8*)&sT[j * 72 + mc];
        }
        if (store_out) {
            for (int q = tid; q < 64 * 16; q += 256) {
                int ml = q >> 4, jc = (q & 15) * 8;
                int m = m0 + ml;
                if (m < NN)
                    *(bf16x8*)&outT[((size_t)b * NN + m) * HH + jc] = *(const bf16x8*)&sO[ml * 136 + jc];
            }
        }
    }
}

// ---------------- GRU cell, MFMA, 32 rows/block; writes next-t x into Gfull0 row0 ----------------
__global__ __launch_bounds__(256) void k_gru_mfma(const __bf16* __restrict__ Xb,
                                                  float* __restrict__ hg,
                                                  __bf16* __restrict__ Hb,
                                                  const __bf16* __restrict__ WihB,
                                                  const __bf16* __restrict__ WhhB,
                                                  const float* __restrict__ bih,
                                                  const float* __restrict__ bhh,
                                                  const float* __restrict__ inp,
                                                  __bf16* __restrict__ G0,
                                                  int tnext) {
    __shared__ float sB[512];
    int tid = threadIdx.x;
    int wave = tid >> 6, lane = tid & 63;
    int lr = lane & 15, lk = lane >> 4;
    int wm = wave & 1, wo = wave >> 1;
    int r0 = blockIdx.x * 32 + wm * 16;
    if (tid < 128) {
        sB[tid] = bih[tid] + bhh[tid];
        sB[128 + tid] = bih[128 + tid] + bhh[128 + tid];
        sB[256 + tid] = bih[256 + tid];
        sB[384 + tid] = bhh[256 + tid];
    }
    __syncthreads();

    f32x4 rz[8], ni[4], nh[4];
#pragma unroll
    for (int i = 0; i < 8; i++) rz[i] = (f32x4){0.f, 0.f, 0.f, 0.f};
#pragma unroll
    for (int i = 0; i < 4; i++) { ni[i] = (f32x4){0.f, 0.f, 0.f, 0.f}; nh[i] = (f32x4){0.f, 0.f, 0.f, 0.f}; }

    int arow = r0 + lr;
#pragma unroll
    for (int kk = 0; kk < 128; kk += 32) {
        bf16x8 xa = *(const bf16x8*)&Xb[(size_t)arow * HH + kk + lk * 8];
        bf16x8 ha = *(const bf16x8*)&Hb[(size_t)arow * HH + kk + lk * 8];
#pragma unroll
        for (int q = 0; q < 4; q++) {
            int orr = wo * 64 + q * 16 + lr;
            bf16x8 w0 = *(const bf16x8*)&WihB[(size_t)orr * HH + kk + lk * 8];
            rz[q] = __builtin_amdgcn_mfma_f32_16x16x32_bf16(xa, w0, rz[q], 0, 0, 0);
            bf16x8 w1 = *(const bf16x8*)&WhhB[(size_t)orr * HH + kk + lk * 8];
            rz[q] = __builtin_amdgcn_mfma_f32_16x16x32_bf16(ha, w1, rz[q], 0, 0, 0);
            bf16x8 w2 = *(const bf16x8*)&WihB[(size_t)(128 + orr) * HH + kk + lk * 8];
            rz[4 + q] = __builtin_amdgcn_mfma_f32_16x16x32_bf16(xa, w2, rz[4 + q], 0, 0, 0);
            bf16x8 w3 = *(const bf16x8*)&WhhB[(size_t)(128 + orr) * HH + kk + lk * 8];
            rz[4 + q] = __builtin_amdgcn_mfma_f32_16x16x32_bf16(ha, w3, rz[4 + q], 0, 0, 0);
            bf16x8 w4 = *(const bf16x8*)&WihB[(size_t)(256 + orr) * HH + kk + lk * 8];
            ni[q] = __builtin_amdgcn_mfma_f32_16x16x32_bf16(xa, w4, ni[q], 0, 0, 0);
            bf16x8 w5 = *(const bf16x8*)&WhhB[(size_t)(256 + orr) * HH + kk + lk * 8];
            nh[q] = __builtin_amdgcn_mfma_f32_16x16x32_bf16(ha, w5, nh[q], 0, 0, 0);
        }
    }
#pragma unroll
    for (int q = 0; q < 4; q++) {
        int j = wo * 64 + q * 16 + lr;
        float br = sB[j], bz = sB[128 + j], bni = sB[256 + j], bnh = sB[384 + j];
#pragma unroll
        for (int i = 0; i < 4; i++) {
            int row = r0 + lk * 4 + i;
            float rg = sigmoidf_(rz[q][i] + br);
            float zg = sigmoidf_(rz[4 + q][i] + bz);
            float hv = hg[(size_t)row * HH + j];
            float ng = tanhf(ni[q][i] + bni + rg * (nh[q][i] + bnh));
            float hp = (1.f - zg) * ng + zg * hv;
            hg[(size_t)row * HH + j] = hp;
            Hb[(size_t)row * HH + j] = (__bf16)hp;
        }
    }
    if (wo == 0 && lr == 0 && tnext < TT) {
#pragma unroll
        for (int i = 0; i < 4; i++) {
            int row = r0 + lk * 4 + i;
            int bb = row / NN, n = row - bb * NN;
            G0[(size_t)bb * GR * KP + n] = (__bf16)inp[(size_t)bb * TT * NN + tnext * NN + n];
        }
    }
}

// ---------------- head: proj -> relu MLP -> out, MFMA ----------------
__global__ __launch_bounds__(256) void k_head_mfma(const __bf16* __restrict__ Hb,
                                                   const __bf16* __restrict__ projB,
                                                   const float* __restrict__ pb,
                                                   const __bf16* __restrict__ w1B,
                                                   const float* __restrict__ b1,
                                                   const __bf16* __restrict__ w2B,
                                                   const float* __restrict__ b2,
                                                   float* __restrict__ out) {
    __shared__ __align__(16) __bf16 sH1[64 * 136];
    __shared__ __align__(16) __bf16 sH2[64 * 264];
    int tid = threadIdx.x;
    int r0 = blockIdx.x * 64;
    int wv = tid >> 6, lane = tid & 63;
    int lr = lane & 15, lk = lane >> 4;
    int arow = r0 + wv * 16 + lr;

    f32x4 a1[8];
#pragma unroll
    for (int i = 0; i < 8; i++) a1[i] = (f32x4){0.f, 0.f, 0.f, 0.f};
#pragma unroll
    for (int kk = 0; kk < 128; kk += 32) {
        bf16x8 xa = *(const bf16x8*)&Hb[(size_t)arow * HH + kk + lk * 8];
#pragma unroll
        for (int f = 0; f < 8; f++) {
            bf16x8 wb = *(const bf16x8*)&projB[(size_t)(f * 16 + lr) * HH + kk + lk * 8];
            a1[f] = __builtin_amdgcn_mfma_f32_16x16x32_bf16(xa, wb, a1[f], 0, 0, 0);
        }
    }
#pragma unroll
    for (int f = 0; f < 8; f++) {
        int j = f * 16 + lr;
        float bv = pb[j];
#pragma unroll
        for (int i = 0; i < 4; i++)
            sH1[(wv * 16 + lk * 4 + i) * 136 + j] = (__bf16)(a1[f][i] + bv);
    }
    __syncthreads();

    f32x4 a2[16];
#pragma unroll
    for (int i = 0; i < 16; i++) a2[i] = (f32x4){0.f, 0.f, 0.f, 0.f};
#pragma unroll
    for (int kk = 0; kk < 128; kk += 32) {
        bf16x8 pa = *(const bf16x8*)&sH1[(wv * 16 + lr) * 136 + kk + lk * 8];
#pragma unroll
        for (int f = 0; f < 16; f++) {
            bf16x8 wb = *(const bf16x8*)&w1B[(size_t)(f * 16 + lr) * HH + kk + lk * 8];
            a2[f] = __builtin_amdgcn_mfma_f32_16x16x32_bf16(pa, wb, a2[f], 0, 0, 0);
        }
    }
    __syncthreads();
#pragma unroll
    for (int f = 0; f < 16; f++) {
        int o = f * 16 + lr;
        float bv = b1[o];
#pragma unroll
        for (int i = 0; i < 4; i++)
            sH2[(wv * 16 + lk * 4 + i) * 264 + o] = (__bf16)fmaxf(a2[f][i] + bv, 0.f);
    }
    __syncthreads();

    f32x4 a3[8];
#pragma unroll
    for (int i = 0; i < 8; i++) a3[i] = (f32x4){0.f, 0.f, 0.f, 0.f};
#pragma unroll
    for (int kk = 0; kk < 256; kk += 32) {
        bf16x8 pa = *(const bf16x8*)&sH2[(wv * 16 + lr) * 264 + kk + lk * 8];
#pragma unroll
        for (int f = 0; f < 8; f++) {
            bf16x8 wb = *(const bf16x8*)&w2B[(size_t)(f * 16 + lr) * 256 + kk + lk * 8];
            a3[f] = __builtin_amdgcn_mfma_f32_16x16x32_bf16(pa, wb, a3[f], 0, 0, 0);
        }
    }
#pragma unroll
    for (int f = 0; f < 8; f++) {
        int j = f * 16 + lr;
        float bv = b2[j];
#pragma unroll
        for (int i = 0; i < 4; i++)
            out[(size_t)(r0 + wv * 16 + lk * 4 + i) * HH + j] = a3[f][i] + bv;
    }
}

extern "C" void kernel_launch(void* const* d_in, const int* in_sizes, int n_in,
                              void* d_out, int out_size, void* d_ws, size_t ws_size,
                              hipStream_t stream) {
    const float* inp    = (const float*)d_in[0];
    const float* adj    = (const float*)d_in[1];
    const float* gc1_w  = (const float*)d_in[2];
    const float* gc1_b  = (const float*)d_in[3];
    const float* gc2_w  = (const float*)d_in[4];
    const float* gc2_b  = (const float*)d_in[5];
    const float* ln_g   = (const float*)d_in[6];
    const float* ln_b   = (const float*)d_in[7];
    const float* res_w  = (const float*)d_in[8];
    const float* res_b  = (const float*)d_in[9];
    const float* wih    = (const float*)d_in[10];
    const float* whh    = (const float*)d_in[11];
    const float* bih    = (const float*)d_in[12];
    const float* bhh    = (const float*)d_in[13];
    const float* proj_w = (const float*)d_in[14];
    const float* proj_b = (const float*)d_in[15];
    const float* ow1    = (const float*)d_in[16];
    const float* ob1    = (const float*)d_in[17];
    const float* ow2    = (const float*)d_in[18];
    const float* ob2    = (const float*)d_in[19];
    float* out = (float*)d_out;

    char* ws = (char*)d_ws;
    size_t off = 0;
    __bf16* Lb     = (__bf16*)(ws + off); off += (size_t)KP * KP * 2;          // 2 MB
    __bf16* Gfull0 = (__bf16*)(ws + off); off += (size_t)BB * GR * KP * 2;     // 5 MB
    __bf16* Gfull1 = (__bf16*)(ws + off); off += (size_t)BB * GR * KP * 2;
    __bf16* GfullB = (__bf16*)(ws + off); off += (size_t)BB * GR * KP * 2;
    size_t zgrp1 = off;
    float* h0   = (float*)(ws + off);  off += (size_t)NROW * HH * 4;
    float* h1   = (float*)(ws + off);  off += (size_t)NROW * HH * 4;
    float* hg   = (float*)(ws + off);  off += (size_t)NROW * HH * 4;
    __bf16* Hb  = (__bf16*)(ws + off); off += (size_t)NROW * HH * 2;
    float* u    = (float*)(ws + off);  off += (size_t)NROW * HH * 4;
    __bf16* outT= (__bf16*)(ws + off); off += (size_t)NROW * HH * 2;
    float* xB   = (float*)(ws + off);  off += NROW * 4;
    __bf16* W1t = (__bf16*)(ws + off); off += (size_t)2 * 256 * CP2 * 2;
    __bf16* W2t = (__bf16*)(ws + off); off += (size_t)2 * 128 * CP2 * 2;
    __bf16* WihB= (__bf16*)(ws + off); off += 49152 * 2;
    __bf16* WhhB= (__bf16*)(ws + off); off += 49152 * 2;
    __bf16* projB=(__bf16*)(ws + off); off += 16384 * 2;
    __bf16* w1B = (__bf16*)(ws + off); off += 32768 * 2;
    __bf16* w2B = (__bf16*)(ws + off); off += 32768 * 2;
    float* a_sm = u;   // overlay: softmax scratch only used before u's first write

    hipMemsetAsync(Lb, 0, zgrp1, stream);                     // Lb + Gfull0/1/B
    hipMemsetAsync(h0, 0, (size_t)NROW * HH * 8, stream);     // h0, h1
    hipMemsetAsync(hg, 0, (size_t)NROW * HH * 6, stream);     // hg, Hb

    k_softmax<<<NN, 256, 0, stream>>>(adj, a_sm);
    k_build_Lt<<<dim3(16, 16), 256, 0, stream>>>(a_sm, Lb);
    k_prep<<<1184, 256, 0, stream>>>(wih, whh, proj_w, ow1, ow2, gc1_w, gc2_w,
                                     WihB, WhhB, projB, w1B, w2B, W1t, W2t);
    k_prep_x<<<64, 256, 0, stream>>>(inp, Gfull0);

    for (int t = 0; t < TT; t++) {
        const float* xs0 = inp + (size_t)t * NN;
        // layer 0
        k_fused<0><<<256, 256, 0, stream>>>(Lb, Gfull0, W1t, gc1_b, GfullB, u,
                                            nullptr, nullptr, 0, nullptr, nullptr, nullptr, nullptr,
                                            nullptr, nullptr, nullptr, nullptr, 0);
        k_fused<1><<<256, 256, 0, stream>>>(Lb, GfullB, W2t, gc2_b, nullptr, u, h0,
                                            xs0, TT * NN, res_w, res_b, ln_g, ln_b,
                                            xB, Gfull1, Gfull0, nullptr, 0);
        // layer 1
        k_fused<0><<<256, 256, 0, stream>>>(Lb, Gfull1, W1t + 256 * CP2, gc1_b + 256, GfullB, u,
                                            nullptr, nullptr, 0, nullptr, nullptr, nullptr, nullptr,
                                            nullptr, nullptr, nullptr, nullptr, 0);
        k_fused<1><<<256, 256, 0, stream>>>(Lb, GfullB, W2t + 128 * CP2, gc2_b + 128, nullptr, u, h1,
                                            xB, NN, res_w, res_b, ln_g + 128, ln_b + 128,
                                            nullptr, nullptr, Gfull1, outT, 1);
        k_gru_mfma<<<500, 256, 0, stream>>>(outT, hg, Hb, WihB, WhhB, bih, bhh,
                                            inp, Gfull0, t + 1);
    }
    k_head_mfma<<<250, 256, 0, stream>>>(Hb, projB, proj_b, w1B, ob1, w2B, ob2, out);
}

// Round 6
// 1873.993 us; speedup vs baseline: 1.2858x; 1.2858x over previous
//
#include <hip/hip_runtime.h>
#include <math.h>

// TGCN: B=16, T=12, N=1000, H=128, NL=2
#define BB 16
#define TT 12
#define NN 1000
#define HH 128
#define CC 129
#define NROW 16000
#define GR 160            // Gfull rows per b (0:x, 1..128:h^T, 129..159:zero)
#define KP 1024           // k / col dim of Gfull rows
#define CP2 160           // stage-2 K (c padded)
#define SPS 168           // sP stride (bf16)

typedef __attribute__((ext_vector_type(4))) float f32x4;
typedef __attribute__((ext_vector_type(8))) __bf16 bf16x8;

__device__ __forceinline__ float sigmoidf_(float x) { return 1.0f / (1.0f + expf(-x)); }

// ---------------- laplacian ----------------
__global__ void k_softmax(const float* __restrict__ adj, float* __restrict__ a) {
    int i = blockIdx.x;
    int t = threadIdx.x;
    __shared__ float red[256];
    float m = -1e30f;
    for (int j = t; j < NN; j += 256) m = fmaxf(m, adj[i * NN + j]);
    red[t] = m; __syncthreads();
    for (int s = 128; s > 0; s >>= 1) { if (t < s) red[t] = fmaxf(red[t], red[t + s]); __syncthreads(); }
    m = red[0]; __syncthreads();
    float sum = 0.f;
    for (int j = t; j < NN; j += 256) sum += expf(adj[i * NN + j] - m);
    red[t] = sum; __syncthreads();
    for (int s = 128; s > 0; s >>= 1) { if (t < s) red[t] += red[t + s]; __syncthreads(); }
    float inv = 1.0f / red[0];
    for (int j = t; j < NN; j += 256) a[i * NN + j] = expf(adj[i * NN + j] - m) * inv;
}

__global__ __launch_bounds__(256) void k_build_Lt(const float* __restrict__ a, __bf16* __restrict__ Lb) {
    __shared__ float s[64][65];
    int bi = blockIdx.x * 64;
    int bj = blockIdx.y * 64;
    int t = threadIdx.x;
    for (int q = t; q < 64 * 64; q += 256) {
        int r = q >> 6, c = q & 63;
        int jj = bj + r, ii = bi + c;
        s[r][c] = (jj < NN && ii < NN) ? a[jj * NN + ii] : 0.f;
    }
    __syncthreads();
    for (int q = t; q < 64 * 64; q += 256) {
        int r = q >> 6, c = q & 63;
        int ii = bi + r, jj = bj + c;
        if (ii < NN && jj < NN)
            Lb[(size_t)ii * KP + jj] = (__bf16)(0.5f * (s[c][r] + (ii == jj ? 1.0f : 0.0f)));
    }
}

// ---------------- one-time weight prep ----------------
__global__ void k_prep(const float* __restrict__ wih, const float* __restrict__ whh,
                       const float* __restrict__ proj_w, const float* __restrict__ ow1,
                       const float* __restrict__ ow2, const float* __restrict__ gc1_w,
                       const float* __restrict__ gc2_w,
                       __bf16* __restrict__ WihB, __bf16* __restrict__ WhhB,
                       __bf16* __restrict__ projB, __bf16* __restrict__ w1B,
                       __bf16* __restrict__ w2B, __bf16* __restrict__ W1t,
                       __bf16* __restrict__ W2t) {
    int idx = blockIdx.x * 256 + threadIdx.x;
    if (idx < 49152) { WihB[idx] = (__bf16)wih[idx]; return; }
    idx -= 49152;
    if (idx < 49152) { WhhB[idx] = (__bf16)whh[idx]; return; }
    idx -= 49152;
    if (idx < 16384) { projB[idx] = (__bf16)proj_w[idx]; return; }
    idx -= 16384;
    if (idx < 32768) { w1B[idx] = (__bf16)ow1[idx]; return; }
    idx -= 32768;
    if (idx < 32768) { w2B[idx] = (__bf16)ow2[idx]; return; }
    idx -= 32768;
    if (idx < 2 * 256 * CP2) {
        int l = idx / (256 * CP2); int r = idx % (256 * CP2); int o = r / CP2, c = r % CP2;
        W1t[idx] = (c < CC) ? (__bf16)gc1_w[((size_t)l * CC + c) * 256 + o] : (__bf16)0.f;
        return;
    }
    idx -= 2 * 256 * CP2;
    if (idx < 2 * 128 * CP2) {
        int l = idx / (128 * CP2); int r = idx % (128 * CP2); int o = r / CP2, c = r % CP2;
        W2t[idx] = (c < CC) ? (__bf16)gc2_w[((size_t)l * CC + c) * 128 + o] : (__bf16)0.f;
    }
}

// Gfull0 row0 = x at t=0
__global__ void k_prep_x(const float* __restrict__ inp, __bf16* __restrict__ G0) {
    int idx = blockIdx.x * 256 + threadIdx.x;
    if (idx >= BB * 1024) return;
    int b = idx >> 10, k = idx & 1023;
    G0[(size_t)b * GR * KP + k] = (k < NN) ? (__bf16)inp[(size_t)b * TT * NN + k] : (__bf16)0.f;
}

// ---------------- fused graph-conv + weight matmul + epilogue ----------------
// 512 threads = 8 waves: wm = m-half (32 rows), wcg = c-group {0:3f,1:2f,2:2f,3:2f}.
// Stage 1: LDS double-buffered via global_load_lds(16B), XOR-swizzled [row][128B] tiles.
//   P[m=64][c=144] = sum_k L[m0+m,k] * Gfull[b][c,k], K=1024 in 16 steps of 64.
// Stage 2: S[m][o] = sum_c P[m,c] * Wt[o,c]  (K=160; o split across 8 waves)
template<int MODE>
__global__ __launch_bounds__(512) void k_fused(
    const __bf16* __restrict__ Lb, const __bf16* __restrict__ Gfull,
    const __bf16* __restrict__ Wt, const float* __restrict__ bias,
    __bf16* __restrict__ GB, float* __restrict__ u, float* __restrict__ h,
    const float* __restrict__ x_in, int xstride,
    const float* __restrict__ res_w, const float* __restrict__ res_b,
    const float* __restrict__ ln_g, const float* __restrict__ ln_b,
    float* __restrict__ x_out, __bf16* __restrict__ Gnext,
    __bf16* __restrict__ GhSelf, __bf16* __restrict__ outT, int store_out) {
    // LDS map: sA dbuf [2][64*128B] @0 (16K); sB dbuf [2][144*128B] @16384 (36K);
    //          sP [64][168] bf16 @53248 (21.5K). Epilogue overlays @0: sGT/sT/sO/sSt.
    __shared__ __align__(16) char smem[74752];
    __shared__ float sScal[640];
    __bf16* sP = (__bf16*)(smem + 53248);
    __bf16* sGT = (__bf16*)smem;                  // MODE0 [256][72]
    __bf16* sT = (__bf16*)smem;                   // MODE1 [128][72]
    __bf16* sO = (__bf16*)(smem + 18432);         // MODE1 [64][136]
    float* sSt = (float*)(smem + 35840);          // MODE1 [2][8][64]

    int tid = threadIdx.x;
    int wg = blockIdx.x;
    int b = wg & 15;                 // b%8 == XCD id -> G[b] home-L2
    int m0 = (wg >> 4) * 64;
    int wave = tid >> 6, lane = tid & 63;
    int lr = lane & 15, lk = lane >> 4;
    int wm = wave >> 2;              // m-half
    int wcg = wave & 3;              // c-group
    int cgbase = (wcg == 0) ? 0 : (wcg == 1 ? 48 : (wcg == 2 ? 80 : 112));
    int NC = (wcg == 0) ? 3 : 2;

    if (MODE == 0) {
        if (tid < 256) sScal[tid] = bias[tid];
    } else {
        if (tid < 128) {
            sScal[tid] = bias[tid];
            sScal[128 + tid] = res_w[tid];
            sScal[256 + tid] = res_b[tid];
            sScal[384 + tid] = ln_g[tid];
            sScal[512 + tid] = ln_b[tid];
        }
    }

    // per-lane source column swizzle: dst byte-in-row = (lane&7)*16, row-in-chunk = lane>>3
    int cswz = (((lane & 7) ^ (lane >> 3)) << 3);   // in bf16 elems (x8)
    int rIn = lane >> 3;                            // row within 8-row chunk

#define GL16(SRC, DST)                                                               \
    __builtin_amdgcn_global_load_lds(                                                \
        (const __attribute__((address_space(1))) unsigned int*)(SRC),                \
        (__attribute__((address_space(3))) unsigned int*)(DST), 16, 0, 0)

#define STAGE_ALL(BUF, KK)                                                           \
    {                                                                                \
        _Pragma("unroll")                                                            \
        for (int jc = 0; jc < 4; jc++) {                                             \
            int ch = wave + jc * 8;                                                  \
            if (ch < 26) {                                                           \
                if (ch < 8) {                                                        \
                    GL16(Lb + (size_t)(m0 + ch * 8 + rIn) * KP + (KK) + cswz,        \
                         smem + (BUF) * 8192 + ch * 1024);                           \
                } else {                                                             \
                    int r8 = ch - 8;                                                 \
                    GL16(Gfull + ((size_t)b * GR + r8 * 8 + rIn) * KP + (KK) + cswz, \
                         smem + 16384 + (BUF) * 18432 + r8 * 1024);                  \
                }                                                                    \
            }                                                                        \
        }                                                                            \
    }

    f32x4 acc[2][3];
#pragma unroll
    for (int i = 0; i < 2; i++)
#pragma unroll
        for (int j = 0; j < 3; j++) acc[i][j] = (f32x4){0.f, 0.f, 0.f, 0.f};

    STAGE_ALL(0, 0);
    __syncthreads();
    int buf = 0;
    for (int it = 0; it < 16; ++it) {
        if (it < 15) STAGE_ALL(buf ^ 1, (it + 1) * 64);
#pragma unroll
        for (int ks = 0; ks < 2; ks++) {
            int kb = ks * 64 + lk * 16;   // byte offset within 128B row
            bf16x8 af[2];
#pragma unroll
            for (int mf = 0; mf < 2; mf++) {
                int rowA = wm * 32 + mf * 16 + lr;
                af[mf] = *(const bf16x8*)(smem + buf * 8192 + rowA * 128 + (kb ^ ((rowA & 7) << 4)));
            }
#pragma unroll
            for (int cf = 0; cf < 3; cf++) {
                if (cf < NC) {
                    int rowB = cgbase + cf * 16 + lr;
                    bf16x8 bfr = *(const bf16x8*)(smem + 16384 + buf * 18432 + rowB * 128 + (kb ^ ((rowB & 7) << 4)));
                    acc[0][cf] = __builtin_amdgcn_mfma_f32_16x16x32_bf16(af[0], bfr, acc[0][cf], 0, 0, 0);
                    acc[1][cf] = __builtin_amdgcn_mfma_f32_16x16x32_bf16(af[1], bfr, acc[1][cf], 0, 0, 0);
                }
            }
        }
        __syncthreads();
        buf ^= 1;
    }

    // P -> sP bf16 (D layout: m = wm*32+mf*16+lk*4+i, c = cgbase+cf*16+lr)
#pragma unroll
    for (int mf = 0; mf < 2; mf++)
#pragma unroll
        for (int cf = 0; cf < 3; cf++) {
            if (cf < NC) {
#pragma unroll
                for (int i = 0; i < 4; i++)
                    sP[(wm * 32 + mf * 16 + lk * 4 + i) * SPS + cgbase + cf * 16 + lr] =
                        (__bf16)acc[mf][cf][i];
            }
        }
    for (int q = tid; q < 64 * 16; q += 512) sP[(q >> 4) * SPS + 144 + (q & 15)] = (__bf16)0.f;
    __syncthreads();

    // Stage 2: o split across 8 waves
    constexpr int NOF = (MODE == 0) ? 2 : 1;
    int o0 = wave * NOF * 16;
    f32x4 accs[4][NOF];
#pragma unroll
    for (int i = 0; i < 4; i++)
#pragma unroll
        for (int j = 0; j < NOF; j++) accs[i][j] = (f32x4){0.f, 0.f, 0.f, 0.f};
#pragma unroll
    for (int kk2 = 0; kk2 < CP2; kk2 += 32) {
        bf16x8 pa[4];
#pragma unroll
        for (int mf2 = 0; mf2 < 4; mf2++)
            pa[mf2] = *(const bf16x8*)&sP[(mf2 * 16 + lr) * SPS + kk2 + lk * 8];
#pragma unroll
        for (int of = 0; of < NOF; of++) {
            bf16x8 wb = *(const bf16x8*)&Wt[(size_t)(o0 + of * 16 + lr) * CP2 + kk2 + lk * 8];
#pragma unroll
            for (int mf2 = 0; mf2 < 4; mf2++)
                accs[mf2][of] = __builtin_amdgcn_mfma_f32_16x16x32_bf16(pa[mf2], wb, accs[mf2][of], 0, 0, 0);
        }
    }

    if (MODE == 0) {
        if (tid < 8)
            *(bf16x8*)&GB[(size_t)b * GR * KP + m0 + tid * 8] =
                *(const bf16x8*)&Gfull[(size_t)b * GR * KP + m0 + tid * 8];
        bool clean = (m0 + 64 <= 500);
        if (clean) {
#pragma unroll
            for (int mf2 = 0; mf2 < 4; mf2++)
#pragma unroll
                for (int of = 0; of < NOF; of++) {
                    int o = o0 + of * 16 + lr;
                    float bv = sScal[o];
#pragma unroll
                    for (int i = 0; i < 4; i++)
                        sGT[o * 72 + mf2 * 16 + lk * 4 + i] = (__bf16)sigmoidf_(accs[mf2][of][i] + bv);
                }
            __syncthreads();
            for (int q = tid; q < 128 * 16; q += 512) {
                int j = q >> 4;
                int rnc = (q & 15) * 4;
                size_t gidx = ((size_t)b * GR + 1 + j) * KP + 2 * m0 + rnc * 2;
                bf16x8 hv = *(const bf16x8*)&Gfull[gidx];
                bf16x8 rv;
#pragma unroll
                for (int e = 0; e < 8; e++) {
                    int rnl = rnc + (e >> 1);
                    int hi = e & 1;
                    float g = (float)sGT[(hi * 128 + j) * 72 + rnl];
                    rv[e] = (__bf16)(g * (float)hv[e]);
                }
                *(bf16x8*)&GB[gidx] = rv;
            }
        } else {
#pragma unroll
            for (int mf2 = 0; mf2 < 4; mf2++)
#pragma unroll
                for (int of = 0; of < NOF; of++) {
                    int o = o0 + of * 16 + lr;
                    int j = o & 127, hi = o >> 7;
                    float bv = sScal[o];
#pragma unroll
                    for (int i = 0; i < 4; i++) {
                        int m = m0 + mf2 * 16 + lk * 4 + i;
                        if (m >= NN) continue;
                        float g = sigmoidf_(accs[mf2][of][i] + bv);
                        if (m < 500) {
                            size_t gi = ((size_t)b * GR + 1 + j) * KP + 2 * m + hi;
                            GB[gi] = (__bf16)(g * (float)Gfull[gi]);
                        } else {
                            u[((size_t)b * NN + 2 * (m - 500) + hi) * HH + j] = g;
                        }
                    }
                }
        }
    } else {
        int j = o0 + lr;   // NOF==1
        float hnv[4][4];
        float s_[4][4], ss_[4][4];
#pragma unroll
        for (int a = 0; a < 4; a++)
#pragma unroll
            for (int i = 0; i < 4; i++) { s_[a][i] = 0.f; ss_[a][i] = 0.f; }
        float b2v = sScal[j], rwv = sScal[128 + j], rbv = sScal[256 + j];
#pragma unroll
        for (int mf2 = 0; mf2 < 4; mf2++) {
#pragma unroll
            for (int i = 0; i < 4; i++) {
                int m = m0 + mf2 * 16 + lk * 4 + i;
                int msafe = (m < NN) ? m : (NN - 1);
                size_t ri = ((size_t)b * NN + msafe) * HH + j;
                float cv = tanhf(accs[mf2][0][i] + b2v);
                float uu = u[ri];
                float hv = h[ri];
                float hn = uu * hv + (1.f - uu) * cv;
                if (m < NN) h[ri] = hn;
                hnv[mf2][i] = hn;
                float xv = (m < NN) ? x_in[(size_t)b * xstride + m] : 0.f;
                float y = hn + xv * rwv + rbv;
                accs[mf2][0][i] = y;
                s_[mf2][i] += y; ss_[mf2][i] += y * y;
            }
        }
#pragma unroll
        for (int msk = 1; msk < 16; msk <<= 1)
#pragma unroll
            for (int a = 0; a < 4; a++)
#pragma unroll
                for (int i = 0; i < 4; i++) {
                    s_[a][i] += __shfl_xor(s_[a][i], msk);
                    ss_[a][i] += __shfl_xor(ss_[a][i], msk);
                }
        if (lr == 0) {
#pragma unroll
            for (int a = 0; a < 4; a++)
#pragma unroll
                for (int i = 0; i < 4; i++) {
                    int ml = a * 16 + lk * 4 + i;
                    sSt[wave * 64 + ml] = s_[a][i];
                    sSt[512 + wave * 64 + ml] = ss_[a][i];
                }
        }
        __syncthreads();
        float mu_[4][4], rs_[4][4];
#pragma unroll
        for (int a = 0; a < 4; a++)
#pragma unroll
            for (int i = 0; i < 4; i++) {
                int ml = a * 16 + lk * 4 + i;
                float S = 0.f, SS = 0.f;
#pragma unroll
                for (int w = 0; w < 8; w++) { S += sSt[w * 64 + ml]; SS += sSt[512 + w * 64 + ml]; }
                float mu = S * (1.f / 128.f);
                float var = SS * (1.f / 128.f) - mu * mu;
                mu_[a][i] = mu;
                rs_[a][i] = rsqrtf(var + 1e-5f);
            }
        float xs_[4][4];
        float lg = sScal[384 + j], lb2 = sScal[512 + j];
#pragma unroll
        for (int mf2 = 0; mf2 < 4; mf2++)
#pragma unroll
            for (int i = 0; i < 4; i++) {
                float ov = (accs[mf2][0][i] - mu_[mf2][i]) * rs_[mf2][i] * lg + lb2;
                accs[mf2][0][i] = ov;
                xs_[mf2][i] = ov;
            }
#pragma unroll
        for (int msk = 1; msk < 16; msk <<= 1)
#pragma unroll
            for (int a = 0; a < 4; a++)
#pragma unroll
                for (int i = 0; i < 4; i++) xs_[a][i] += __shfl_xor(xs_[a][i], msk);
        __syncthreads();
        if (lr == 0) {
#pragma unroll
            for (int a = 0; a < 4; a++)
#pragma unroll
                for (int i = 0; i < 4; i++)
                    sSt[wave * 64 + a * 16 + lk * 4 + i] = xs_[a][i];
        }
        __syncthreads();
        if (wave == 0 && lr == 0) {
#pragma unroll
            for (int a = 0; a < 4; a++)
#pragma unroll
                for (int i = 0; i < 4; i++) {
                    int ml = a * 16 + lk * 4 + i;
                    int m = m0 + ml;
                    if (m < NN) {
                        float S = 0.f;
#pragma unroll
                        for (int w = 0; w < 8; w++) S += sSt[w * 64 + ml];
                        float xv = S * (1.f / 128.f);
                        if (x_out) x_out[(size_t)b * NN + m] = xv;
                        if (Gnext) Gnext[(size_t)b * GR * KP + m] = (__bf16)xv;
                    }
                }
        }
        // hn -> GhSelf (transposed), out -> outT
#pragma unroll
        for (int mf2 = 0; mf2 < 4; mf2++)
#pragma unroll
            for (int i = 0; i < 4; i++)
                sT[j * 72 + mf2 * 16 + lk * 4 + i] = (__bf16)hnv[mf2][i];
        if (store_out) {
#pragma unroll
            for (int mf2 = 0; mf2 < 4; mf2++)
#pragma unroll
                for (int i = 0; i < 4; i++)
                    sO[(mf2 * 16 + lk * 4 + i) * 136 + j] = (__bf16)accs[mf2][0][i];
        }
        __syncthreads();
        for (int q = tid; q < 128 * 8; q += 512) {
            int jj = q >> 3, mc = (q & 7) * 8;
            if (m0 + mc < NN)
                *(bf16x8*)&GhSelf[((size_t)b * GR + 1 + jj) * KP + m0 + mc] = *(const bf16x8*)&sT[jj * 72 + mc];
        }
        if (store_out) {
            for (int q = tid; q < 64 * 16; q += 512) {
                int ml = q >> 4, jc = (q & 15) * 8;
                int m = m0 + ml;
                if (m < NN)
                    *(bf16x8*)&outT[((size_t)b * NN + m) * HH + jc] = *(const bf16x8*)&sO[ml * 136 + jc];
            }
        }
    }
#undef STAGE_ALL
#undef GL16
}

// ---------------- GRU cell, MFMA, 32 rows/block; writes next-t x into Gfull0 row0 ----------------
__global__ __launch_bounds__(256) void k_gru_mfma(const __bf16* __restrict__ Xb,
                                                  float* __restrict__ hg,
                                                  __bf16* __restrict__ Hb,
                                                  const __bf16* __restrict__ WihB,
                                                  const __bf16* __restrict__ WhhB,
                                                  const float* __restrict__ bih,
                                                  const float* __restrict__ bhh,
                                                  const float* __restrict__ inp,
                                                  __bf16* __restrict__ G0,
                                                  int tnext) {
    __shared__ float sB[512];
    int tid = threadIdx.x;
    int wave = tid >> 6, lane = tid & 63;
    int lr = lane & 15, lk = lane >> 4;
    int wm = wave & 1, wo = wave >> 1;
    int r0 = blockIdx.x * 32 + wm * 16;
    if (tid < 128) {
        sB[tid] = bih[tid] + bhh[tid];
        sB[128 + tid] = bih[128 + tid] + bhh[128 + tid];
        sB[256 + tid] = bih[256 + tid];
        sB[384 + tid] = bhh[256 + tid];
    }
    __syncthreads();

    f32x4 rz[8], ni[4], nh[4];
#pragma unroll
    for (int i = 0; i < 8; i++) rz[i] = (f32x4){0.f, 0.f, 0.f, 0.f};
#pragma unroll
    for (int i = 0; i < 4; i++) { ni[i] = (f32x4){0.f, 0.f, 0.f, 0.f}; nh[i] = (f32x4){0.f, 0.f, 0.f, 0.f}; }

    int arow = r0 + lr;
#pragma unroll
    for (int kk = 0; kk < 128; kk += 32) {
        bf16x8 xa = *(const bf16x8*)&Xb[(size_t)arow * HH + kk + lk * 8];
        bf16x8 ha = *(const bf16x8*)&Hb[(size_t)arow * HH + kk + lk * 8];
#pragma unroll
        for (int q = 0; q < 4; q++) {
            int orr = wo * 64 + q * 16 + lr;
            bf16x8 w0 = *(const bf16x8*)&WihB[(size_t)orr * HH + kk + lk * 8];
            rz[q] = __builtin_amdgcn_mfma_f32_16x16x32_bf16(xa, w0, rz[q], 0, 0, 0);
            bf16x8 w1 = *(const bf16x8*)&WhhB[(size_t)orr * HH + kk + lk * 8];
            rz[q] = __builtin_amdgcn_mfma_f32_16x16x32_bf16(ha, w1, rz[q], 0, 0, 0);
            bf16x8 w2 = *(const bf16x8*)&WihB[(size_t)(128 + orr) * HH + kk + lk * 8];
            rz[4 + q] = __builtin_amdgcn_mfma_f32_16x16x32_bf16(xa, w2, rz[4 + q], 0, 0, 0);
            bf16x8 w3 = *(const bf16x8*)&WhhB[(size_t)(128 + orr) * HH + kk + lk * 8];
            rz[4 + q] = __builtin_amdgcn_mfma_f32_16x16x32_bf16(ha, w3, rz[4 + q], 0, 0, 0);
            bf16x8 w4 = *(const bf16x8*)&WihB[(size_t)(256 + orr) * HH + kk + lk * 8];
            ni[q] = __builtin_amdgcn_mfma_f32_16x16x32_bf16(xa, w4, ni[q], 0, 0, 0);
            bf16x8 w5 = *(const bf16x8*)&WhhB[(size_t)(256 + orr) * HH + kk + lk * 8];
            nh[q] = __builtin_amdgcn_mfma_f32_16x16x32_bf16(ha, w5, nh[q], 0, 0, 0);
        }
    }
#pragma unroll
    for (int q = 0; q < 4; q++) {
        int j = wo * 64 + q * 16 + lr;
        float br = sB[j], bz = sB[128 + j], bni = sB[256 + j], bnh = sB[384 + j];
#pragma unroll
        for (int i = 0; i < 4; i++) {
            int row = r0 + lk * 4 + i;
            float rg = sigmoidf_(rz[q][i] + br);
            float zg = sigmoidf_(rz[4 + q][i] + bz);
            float hv = hg[(size_t)row * HH + j];
            float ng = tanhf(ni[q][i] + bni + rg * (nh[q][i] + bnh));
            float hp = (1.f - zg) * ng + zg * hv;
            hg[(size_t)row * HH + j] = hp;
            Hb[(size_t)row * HH + j] = (__bf16)hp;
        }
    }
    if (wo == 0 && lr == 0 && tnext < TT) {
#pragma unroll
        for (int i = 0; i < 4; i++) {
            int row = r0 + lk * 4 + i;
            int bb = row / NN, n = row - bb * NN;
            G0[(size_t)bb * GR * KP + n] = (__bf16)inp[(size_t)bb * TT * NN + tnext * NN + n];
        }
    }
}

// ---------------- head: proj -> relu MLP -> out, MFMA ----------------
__global__ __launch_bounds__(256) void k_head_mfma(const __bf16* __restrict__ Hb,
                                                   const __bf16* __restrict__ projB,
                                                   const float* __restrict__ pb,
                                                   const __bf16* __restrict__ w1B,
                                                   const float* __restrict__ b1,
                                                   const __bf16* __restrict__ w2B,
                                                   const float* __restrict__ b2,
                                                   float* __restrict__ out) {
    __shared__ __align__(16) __bf16 sH1[64 * 136];
    __shared__ __align__(16) __bf16 sH2[64 * 264];
    int tid = threadIdx.x;
    int r0 = blockIdx.x * 64;
    int wv = tid >> 6, lane = tid & 63;
    int lr = lane & 15, lk = lane >> 4;
    int arow = r0 + wv * 16 + lr;

    f32x4 a1[8];
#pragma unroll
    for (int i = 0; i < 8; i++) a1[i] = (f32x4){0.f, 0.f, 0.f, 0.f};
#pragma unroll
    for (int kk = 0; kk < 128; kk += 32) {
        bf16x8 xa = *(const bf16x8*)&Hb[(size_t)arow * HH + kk + lk * 8];
#pragma unroll
        for (int f = 0; f < 8; f++) {
            bf16x8 wb = *(const bf16x8*)&projB[(size_t)(f * 16 + lr) * HH + kk + lk * 8];
            a1[f] = __builtin_amdgcn_mfma_f32_16x16x32_bf16(xa, wb, a1[f], 0, 0, 0);
        }
    }
#pragma unroll
    for (int f = 0; f < 8; f++) {
        int j = f * 16 + lr;
        float bv = pb[j];
#pragma unroll
        for (int i = 0; i < 4; i++)
            sH1[(wv * 16 + lk * 4 + i) * 136 + j] = (__bf16)(a1[f][i] + bv);
    }
    __syncthreads();

    f32x4 a2[16];
#pragma unroll
    for (int i = 0; i < 16; i++) a2[i] = (f32x4){0.f, 0.f, 0.f, 0.f};
#pragma unroll
    for (int kk = 0; kk < 128; kk += 32) {
        bf16x8 pa = *(const bf16x8*)&sH1[(wv * 16 + lr) * 136 + kk + lk * 8];
#pragma unroll
        for (int f = 0; f < 16; f++) {
            bf16x8 wb = *(const bf16x8*)&w1B[(size_t)(f * 16 + lr) * HH + kk + lk * 8];
            a2[f] = __builtin_amdgcn_mfma_f32_16x16x32_bf16(pa, wb, a2[f], 0, 0, 0);
        }
    }
    __syncthreads();
#pragma unroll
    for (int f = 0; f < 16; f++) {
        int o = f * 16 + lr;
        float bv = b1[o];
#pragma unroll
        for (int i = 0; i < 4; i++)
            sH2[(wv * 16 + lk * 4 + i) * 264 + o] = (__bf16)fmaxf(a2[f][i] + bv, 0.f);
    }
    __syncthreads();

    f32x4 a3[8];
#pragma unroll
    for (int i = 0; i < 8; i++) a3[i] = (f32x4){0.f, 0.f, 0.f, 0.f};
#pragma unroll
    for (int kk = 0; kk < 256; kk += 32) {
        bf16x8 pa = *(const bf16x8*)&sH2[(wv * 16 + lr) * 264 + kk + lk * 8];
#pragma unroll
        for (int f = 0; f < 8; f++) {
            bf16x8 wb = *(const bf16x8*)&w2B[(size_t)(f * 16 + lr) * 256 + kk + lk * 8];
            a3[f] = __builtin_amdgcn_mfma_f32_16x16x32_bf16(pa, wb, a3[f], 0, 0, 0);
        }
    }
#pragma unroll
    for (int f = 0; f < 8; f++) {
        int j = f * 16 + lr;
        float bv = b2[j];
#pragma unroll
        for (int i = 0; i < 4; i++)
            out[(size_t)(r0 + wv * 16 + lk * 4 + i) * HH + j] = a3[f][i] + bv;
    }
}

extern "C" void kernel_launch(void* const* d_in, const int* in_sizes, int n_in,
                              void* d_out, int out_size, void* d_ws, size_t ws_size,
                              hipStream_t stream) {
    const float* inp    = (const float*)d_in[0];
    const float* adj    = (const float*)d_in[1];
    const float* gc1_w  = (const float*)d_in[2];
    const float* gc1_b  = (const float*)d_in[3];
    const float* gc2_w  = (const float*)d_in[4];
    const float* gc2_b  = (const float*)d_in[5];
    const float* ln_g   = (const float*)d_in[6];
    const float* ln_b   = (const float*)d_in[7];
    const float* res_w  = (const float*)d_in[8];
    const float* res_b  = (const float*)d_in[9];
    const float* wih    = (const float*)d_in[10];
    const float* whh    = (const float*)d_in[11];
    const float* bih    = (const float*)d_in[12];
    const float* bhh    = (const float*)d_in[13];
    const float* proj_w = (const float*)d_in[14];
    const float* proj_b = (const float*)d_in[15];
    const float* ow1    = (const float*)d_in[16];
    const float* ob1    = (const float*)d_in[17];
    const float* ow2    = (const float*)d_in[18];
    const float* ob2    = (const float*)d_in[19];
    float* out = (float*)d_out;

    char* ws = (char*)d_ws;
    size_t off = 0;
    __bf16* Lb     = (__bf16*)(ws + off); off += (size_t)KP * KP * 2;          // 2 MB
    __bf16* Gfull0 = (__bf16*)(ws + off); off += (size_t)BB * GR * KP * 2;     // 5 MB
    __bf16* Gfull1 = (__bf16*)(ws + off); off += (size_t)BB * GR * KP * 2;
    __bf16* GfullB = (__bf16*)(ws + off); off += (size_t)BB * GR * KP * 2;
    size_t zgrp1 = off;
    float* h0   = (float*)(ws + off);  off += (size_t)NROW * HH * 4;
    float* h1   = (float*)(ws + off);  off += (size_t)NROW * HH * 4;
    float* hg   = (float*)(ws + off);  off += (size_t)NROW * HH * 4;
    __bf16* Hb  = (__bf16*)(ws + off); off += (size_t)NROW * HH * 2;
    float* u    = (float*)(ws + off);  off += (size_t)NROW * HH * 4;
    __bf16* outT= (__bf16*)(ws + off); off += (size_t)NROW * HH * 2;
    float* xB   = (float*)(ws + off);  off += NROW * 4;
    __bf16* W1t = (__bf16*)(ws + off); off += (size_t)2 * 256 * CP2 * 2;
    __bf16* W2t = (__bf16*)(ws + off); off += (size_t)2 * 128 * CP2 * 2;
    __bf16* WihB= (__bf16*)(ws + off); off += 49152 * 2;
    __bf16* WhhB= (__bf16*)(ws + off); off += 49152 * 2;
    __bf16* projB=(__bf16*)(ws + off); off += 16384 * 2;
    __bf16* w1B = (__bf16*)(ws + off); off += 32768 * 2;
    __bf16* w2B = (__bf16*)(ws + off); off += 32768 * 2;
    float* a_sm = u;   // overlay: softmax scratch only used before u's first write

    hipMemsetAsync(Lb, 0, zgrp1, stream);                     // Lb + Gfull0/1/B
    hipMemsetAsync(h0, 0, (size_t)NROW * HH * 8, stream);     // h0, h1
    hipMemsetAsync(hg, 0, (size_t)NROW * HH * 6, stream);     // hg, Hb

    k_softmax<<<NN, 256, 0, stream>>>(adj, a_sm);
    k_build_Lt<<<dim3(16, 16), 256, 0, stream>>>(a_sm, Lb);
    k_prep<<<1184, 256, 0, stream>>>(wih, whh, proj_w, ow1, ow2, gc1_w, gc2_w,
                                     WihB, WhhB, projB, w1B, w2B, W1t, W2t);
    k_prep_x<<<64, 256, 0, stream>>>(inp, Gfull0);

    for (int t = 0; t < TT; t++) {
        const float* xs0 = inp + (size_t)t * NN;
        // layer 0
        k_fused<0><<<256, 512, 0, stream>>>(Lb, Gfull0, W1t, gc1_b, GfullB, u,
                                            nullptr, nullptr, 0, nullptr, nullptr, nullptr, nullptr,
                                            nullptr, nullptr, nullptr, nullptr, 0);
        k_fused<1><<<256, 512, 0, stream>>>(Lb, GfullB, W2t, gc2_b, nullptr, u, h0,
                                            xs0, TT * NN, res_w, res_b, ln_g, ln_b,
                                            xB, Gfull1, Gfull0, nullptr, 0);
        // layer 1
        k_fused<0><<<256, 512, 0, stream>>>(Lb, Gfull1, W1t + 256 * CP2, gc1_b + 256, GfullB, u,
                                            nullptr, nullptr, 0, nullptr, nullptr, nullptr, nullptr,
                                            nullptr, nullptr, nullptr, nullptr, 0);
        k_fused<1><<<256, 512, 0, stream>>>(Lb, GfullB, W2t + 128 * CP2, gc2_b + 128, nullptr, u, h1,
                                            xB, NN, res_w, res_b, ln_g + 128, ln_b + 128,
                                            nullptr, nullptr, Gfull1, outT, 1);
        k_gru_mfma<<<500, 256, 0, stream>>>(outT, hg, Hb, WihB, WhhB, bih, bhh,
                                            inp, Gfull0, t + 1);
    }
    k_head_mfma<<<250, 256, 0, stream>>>(Hb, projB, proj_b, w1B, ob1, w2B, ob2, out);
}